// Round 14
// baseline (96.364 us; speedup 1.0000x reference)
//
#include <hip/hip_runtime.h>
#include <hip/hip_bf16.h>

typedef __attribute__((ext_vector_type(16))) float f32x16;
typedef __attribute__((ext_vector_type(8))) short short8v;
typedef __attribute__((ext_vector_type(8))) unsigned short ushort8v;

#define T_ROWS 16384
#define H_DIM  4096
#define E_NUM  64
#define TOPK   8
#define MROWS  32               // rows per block
#define KC     256              // k-chunk
#define NCH    (H_DIM / KC)     // 16 chunks
#define WIMG   65536            // bytes per W chunk image (frag-slot-ordered)
#define MASK_OFF ((size_t)NCH * WIMG)

__device__ __forceinline__ unsigned short f2bf(float f) {
    unsigned int u = __float_as_uint(f);
    unsigned int r = (u + 0x7fffu + ((u >> 16) & 1u)) >> 16;  // RNE
    return (unsigned short)r;
}
__device__ __forceinline__ float bf2f(unsigned short h) {
    return __uint_as_float(((unsigned int)h) << 16);
}

// ---- prep: frag-slot-ordered W image + allowed-mask ----
// image[ch 0..15][w 0..7][j 0..7][lane 0..63]*16B ; role w: cg=w&1, kh=w>>1 ;
// slot j: plane=j&1 (hi/lo), ks=j>>1 (0..3). Value: 8 bf16 of
// W[cg*32+(lane&31)][ch*256 + kh*64 + ks*16 + (lane>>5)*8 ...]
__global__ __launch_bounds__(256) void prep_w(
    const float* __restrict__ W, unsigned short* __restrict__ WS,
    const int* __restrict__ ids, int nids)
{
    const int g    = blockIdx.x * 256 + threadIdx.x;   // 65536 16B-groups
    const int lane = g & 63;
    const int j    = (g >> 6) & 7;
    const int w    = (g >> 9) & 7;
    const int ch   = g >> 12;
    const int plane = j & 1;
    const int ks    = j >> 1;
    const int row   = (w & 1) * 32 + (lane & 31);
    const int kk    = ch * KC + (w >> 1) * 64 + ks * 16 + (lane >> 5) * 8;
    const float* src = W + (size_t)row * H_DIM + kk;
    ushort8v o;
#pragma unroll
    for (int t = 0; t < 8; ++t) {
        const float f = src[t];
        const unsigned short hb = f2bf(f);
        o[t] = (plane == 0) ? hb : f2bf(f - bf2f(hb));
    }
    *(ushort8v*)((char*)WS + (size_t)g * 16) = o;

    if (blockIdx.x == 0 && threadIdx.x == 0) {
        unsigned long long mb = 0;
        for (int t = 0; t < nids; ++t) {
            const int e = ids[t];
            if (e >= 0 && e < E_NUM) mb |= (1ull << e);
        }
        *(unsigned long long*)((char*)WS + MASK_OFF) = mb;
    }
}

// ---- main: 512 thr = 8 waves; wave (cg=w&1, kh=w>>1) computes a 32x32
// partial over K-quarter kh (64 k per chunk) with mfma_32x32x16;
// B-frags global->regs (8 slots/chunk), X staged via LDS. ----
__global__ __launch_bounds__(512, 4) void router_main(
    const float* __restrict__ X, const unsigned short* __restrict__ WS,
    float* __restrict__ out)
{
    const int tid  = threadIdx.x;
    const int lane = tid & 63;
    const int w    = tid >> 6;        // 0..7
    const int cg   = w & 1;           // experts half
    const int kh   = w >> 1;          // K quarter of the chunk
    const int rb   = blockIdx.x * MROWS;
    const int fr32 = lane & 31;
    const int fo   = lane >> 5;

    __shared__ char LDSRAW[34816];    // X tiles (32 KB) then scoreboard (34 KB)
    char* XH = LDSRAW;                // 16 KB [32][512B swizzled] bf16-hi
    char* XL = LDSRAW + 16384;        // 16 KB bf16-lo

    // staging coords: X 16 f32/thread (two 8-float groups)
    const int srow = tid >> 4;               // 0..31
    const int sc16 = (tid & 15) * 16;        // f32 col base
    const float* xg = X + (size_t)(rb + srow) * H_DIM + sc16;
    const int xsw   = (srow & 15) << 4;
    const int xb0   = srow * 512 + ((sc16 * 2) ^ xsw);
    const int xb1   = srow * 512 + ((sc16 * 2 + 16) ^ xsw);

    // W frag pointer: per wave, per chunk: 8 x 1KB coalesced slots
    const char* wfg = (const char*)WS + (size_t)w * 8192 + (size_t)lane * 16;

    const int arow = fr32;
    const int asw  = (arow & 15) << 4;

    f32x16 acc;
#pragma unroll
    for (int r = 0; r < 16; ++r) acc[r] = 0.f;

    // ---- prologue: chunk-0 registers ----
    float4 px0 = *(const float4*)(xg);
    float4 px1 = *(const float4*)(xg + 4);
    float4 px2 = *(const float4*)(xg + 8);
    float4 px3 = *(const float4*)(xg + 12);
    short8v cA0, cA1, cA2, cA3, cA4, cA5, cA6, cA7;
    short8v cB0, cB1, cB2, cB3, cB4, cB5, cB6, cB7;
    cA0 = *(const short8v*)(wfg);
    cA1 = *(const short8v*)(wfg + 1024);
    cA2 = *(const short8v*)(wfg + 2048);
    cA3 = *(const short8v*)(wfg + 3072);
    cA4 = *(const short8v*)(wfg + 4096);
    cA5 = *(const short8v*)(wfg + 5120);
    cA6 = *(const short8v*)(wfg + 6144);
    cA7 = *(const short8v*)(wfg + 7168);

#define SPLIT8(PA, PB, DST) do {                                             \
        float v[8] = {PA.x, PA.y, PA.z, PA.w, PB.x, PB.y, PB.z, PB.w};       \
        ushort8v hv, lv;                                                     \
        _Pragma("unroll")                                                    \
        for (int t = 0; t < 8; ++t) {                                        \
            const unsigned short hb = f2bf(v[t]);                            \
            hv[t] = hb;                                                      \
            lv[t] = f2bf(v[t] - bf2f(hb));                                   \
        }                                                                    \
        *(ushort8v*)(XH + (DST)) = hv;                                       \
        *(ushort8v*)(XL + (DST)) = lv;                                       \
    } while (0)

#define KSTEP(KS, BH, BL) do {                                               \
        const int kb = kh * 128 + (KS) * 32 + fo * 16;                       \
        short8v ah = *(const short8v*)(XH + arow * 512 + (kb ^ asw));        \
        short8v al = *(const short8v*)(XL + arow * 512 + (kb ^ asw));        \
        acc = __builtin_amdgcn_mfma_f32_32x32x16_bf16(ah, BH, acc, 0, 0, 0); \
        acc = __builtin_amdgcn_mfma_f32_32x32x16_bf16(ah, BL, acc, 0, 0, 0); \
        acc = __builtin_amdgcn_mfma_f32_32x32x16_bf16(al, BH, acc, 0, 0, 0); \
    } while (0)

#define STEP(CH, C0, C1, C2, C3, C4, C5, C6, C7,                             \
                  N0, N1, N2, N3, N4, N5, N6, N7) do {                       \
        __syncthreads();   /* [A] prev compute done reading LDS */           \
        SPLIT8(px0, px1, xb0);                                               \
        SPLIT8(px2, px3, xb1);                                               \
        __syncthreads();   /* [B] X tile ready */                            \
        if ((CH) + 1 < NCH) {                                                \
            const float* xn = xg + ((CH) + 1) * KC;                          \
            px0 = *(const float4*)(xn);                                      \
            px1 = *(const float4*)(xn + 4);                                  \
            px2 = *(const float4*)(xn + 8);                                  \
            px3 = *(const float4*)(xn + 12);                                 \
            const char* wi = wfg + (size_t)((CH) + 1) * WIMG;                \
            N0 = *(const short8v*)(wi);                                      \
            N1 = *(const short8v*)(wi + 1024);                               \
            N2 = *(const short8v*)(wi + 2048);                               \
            N3 = *(const short8v*)(wi + 3072);                               \
            N4 = *(const short8v*)(wi + 4096);                               \
            N5 = *(const short8v*)(wi + 5120);                               \
            N6 = *(const short8v*)(wi + 6144);                               \
            N7 = *(const short8v*)(wi + 7168);                               \
        }                                                                    \
        KSTEP(0, C0, C1);                                                    \
        KSTEP(1, C2, C3);                                                    \
        KSTEP(2, C4, C5);                                                    \
        KSTEP(3, C6, C7);                                                    \
    } while (0)

    for (int ch = 0; ch < NCH; ch += 2) {
        STEP(ch,     cA0, cA1, cA2, cA3, cA4, cA5, cA6, cA7,
                     cB0, cB1, cB2, cB3, cB4, cB5, cB6, cB7);
        STEP(ch + 1, cB0, cB1, cB2, cB3, cB4, cB5, cB6, cB7,
                     cA0, cA1, cA2, cA3, cA4, cA5, cA6, cA7);
    }
#undef STEP
#undef KSTEP
#undef SPLIT8

    // ---- scoreboard: 4 kh-planes [4][32][68] f32, deterministic reduce ----
    __syncthreads();                       // all compute done
    float* sm = (float*)LDSRAW;            // 34816 B exactly
    // C/D layout (m74/m101): col = lane&31, row = (r&3)+8*(r>>2)+4*(lane>>5)
#pragma unroll
    for (int r = 0; r < 16; ++r) {
        const int row = (r & 3) + 8 * (r >> 2) + 4 * fo;
        sm[(kh * 32 + row) * 68 + cg * 32 + fr32] = acc[r];
    }
    __syncthreads();
    if (w >= 2) return;                    // no barriers after this point

    const unsigned long long mbits =
        *(const unsigned long long*)((const char*)WS + MASK_OFF);

    const int fr = lane & 15;
    const int fq = lane >> 4;
    float* o_log = out;
    float* o_rw  = out + (size_t)T_ROWS * E_NUM;
    float* o_se  = o_rw + (size_t)T_ROWS * TOPK;

    // wave w handles rows w*16 .. w*16+15 with the value-verified epilogue
#pragma unroll
    for (int j = 0; j < 4; ++j) {
        const int row_l = w * 16 + fq * 4 + j;
        const int grow  = rb + row_l;
        float a0 = 0.f, a1 = 0.f, a2 = 0.f, a3 = 0.f;
#pragma unroll
        for (int p = 0; p < 4; ++p) {      // fixed-order kh reduction
            a0 += sm[(p * 32 + row_l) * 68 +  0 + fr];
            a1 += sm[(p * 32 + row_l) * 68 + 16 + fr];
            a2 += sm[(p * 32 + row_l) * 68 + 32 + fr];
            a3 += sm[(p * 32 + row_l) * 68 + 48 + fr];
        }
        float mv0 = ((mbits >> ( 0 + fr)) & 1) ? a0 : -10000.0f;
        float mv1 = ((mbits >> (16 + fr)) & 1) ? a1 : -10000.0f;
        float mv2 = ((mbits >> (32 + fr)) & 1) ? a2 : -10000.0f;
        float mv3 = ((mbits >> (48 + fr)) & 1) ? a3 : -10000.0f;
        o_log[(size_t)grow * 64 +  0 + fr] = mv0;
        o_log[(size_t)grow * 64 + 16 + fr] = mv1;
        o_log[(size_t)grow * 64 + 32 + fr] = mv2;
        o_log[(size_t)grow * 64 + 48 + fr] = mv3;

        float m = fmaxf(fmaxf(mv0, mv1), fmaxf(mv2, mv3));
#pragma unroll
        for (int off = 1; off < 16; off <<= 1) m = fmaxf(m, __shfl_xor(m, off));

        float tsum = 0.f, myv = 0.f;
        int   mye  = 0;
#pragma unroll
        for (int t = 0; t < TOPK; ++t) {
            float bv = mv0; int be = fr;
            if (mv1 > bv) { bv = mv1; be = 16 + fr; }
            if (mv2 > bv) { bv = mv2; be = 32 + fr; }
            if (mv3 > bv) { bv = mv3; be = 48 + fr; }
#pragma unroll
            for (int off = 1; off < 16; off <<= 1) {
                float ov = __shfl_xor(bv, off);
                int   oe = __shfl_xor(be, off);
                if (ov > bv || (ov == bv && oe < be)) { bv = ov; be = oe; }
            }
            const float pv = expf(bv - m);
            tsum += pv;
            if (fr == t) { myv = pv; mye = be; }
            if ((be & 15) == fr) {       // owner lane excludes winner
                const int bn = be >> 4;
                if      (bn == 0) mv0 = -3.4e38f;
                else if (bn == 1) mv1 = -3.4e38f;
                else if (bn == 2) mv2 = -3.4e38f;
                else              mv3 = -3.4e38f;
            }
        }
        if (fr < TOPK) {
            o_rw[(size_t)grow * TOPK + fr] = myv / tsum;
            o_se[(size_t)grow * TOPK + fr] = (float)mye;
        }
    }
}

extern "C" void kernel_launch(void* const* d_in, const int* in_sizes, int n_in,
                              void* d_out, int out_size, void* d_ws, size_t ws_size,
                              hipStream_t stream) {
    const float* X   = (const float*)d_in[0];
    const float* W   = (const float*)d_in[1];
    const int*   ids = (const int*)d_in[2];
    const int    nids = in_sizes[2];
    float* out = (float*)d_out;

    unsigned short* WS = (unsigned short*)d_ws;   // 1 MB W image + 8 B mask

    hipLaunchKernelGGL(prep_w, dim3(256), dim3(256), 0, stream, W, WS, ids, nids);
    hipLaunchKernelGGL(router_main, dim3(T_ROWS / MROWS), dim3(512), 0, stream,
                       X, WS, out);
}

// Round 15
// 94.210 us; speedup vs baseline: 1.0229x; 1.0229x over previous
//
#include <hip/hip_runtime.h>
#include <hip/hip_bf16.h>

typedef __attribute__((ext_vector_type(16))) float f32x16;
typedef __attribute__((ext_vector_type(8))) short short8v;
typedef __attribute__((ext_vector_type(8))) unsigned short ushort8v;

#define T_ROWS 16384
#define H_DIM  4096
#define E_NUM  64
#define TOPK   8
#define MROWS  64               // rows per block
#define KC     128              // k-chunk
#define NCH    (H_DIM / KC)     // 32 chunks
#define WIMG   32768            // bytes per W chunk image (frag-slot-ordered)
#define MASK_OFF ((size_t)NCH * WIMG)

__device__ __forceinline__ unsigned short f2bf(float f) {
    unsigned int u = __float_as_uint(f);
    unsigned int r = (u + 0x7fffu + ((u >> 16) & 1u)) >> 16;  // RNE
    return (unsigned short)r;
}
__device__ __forceinline__ float bf2f(unsigned short h) {
    return __uint_as_float(((unsigned int)h) << 16);
}

// ---- prep: frag-slot-ordered W image + allowed-mask ----
// image[ch 0..31][wq 0..3][j 0..7][lane 0..63]*16B ; wq: cg=wq&1, kh=wq>>1 ;
// slot j: plane=j&1 (hi/lo), ks=j>>1 (0..3). Value: 8 bf16 of
// W[cg*32+(lane&31)][ch*128 + kh*64 + ks*16 + (lane>>5)*8 ...]
__global__ __launch_bounds__(256) void prep_w(
    const float* __restrict__ W, unsigned short* __restrict__ WS,
    const int* __restrict__ ids, int nids)
{
    const int g    = blockIdx.x * 256 + threadIdx.x;   // 65536 16B-groups
    const int lane = g & 63;
    const int j    = (g >> 6) & 7;
    const int wq   = (g >> 9) & 3;
    const int ch   = g >> 11;
    const int plane = j & 1;
    const int ks    = j >> 1;
    const int row   = (wq & 1) * 32 + (lane & 31);
    const int kk    = ch * KC + (wq >> 1) * 64 + ks * 16 + (lane >> 5) * 8;
    const float* src = W + (size_t)row * H_DIM + kk;
    ushort8v o;
#pragma unroll
    for (int t = 0; t < 8; ++t) {
        const float f = src[t];
        const unsigned short hb = f2bf(f);
        o[t] = (plane == 0) ? hb : f2bf(f - bf2f(hb));
    }
    *(ushort8v*)((char*)WS + (size_t)g * 16) = o;

    if (blockIdx.x == 0 && threadIdx.x == 0) {
        unsigned long long mb = 0;
        for (int t = 0; t < nids; ++t) {
            const int e = ids[t];
            if (e >= 0 && e < E_NUM) mb |= (1ull << e);
        }
        *(unsigned long long*)((char*)WS + MASK_OFF) = mb;
    }
}

// ---- main: grid 256 (1 block/CU), 512 thr = 8 waves; wave w ->
// (cg=w&1, kh=(w>>1)&1, rg=w>>2): 32 rows x 32 experts over K-half kh
// of each chunk, mfma_32x32x16; W frags global->regs; X via LDS. ----
__global__ __launch_bounds__(512, 2) void router_main(
    const float* __restrict__ X, const unsigned short* __restrict__ WS,
    float* __restrict__ out)
{
    const int tid  = threadIdx.x;
    const int lane = tid & 63;
    const int w    = tid >> 6;        // 0..7
    const int cg   = w & 1;           // experts half
    const int kh   = (w >> 1) & 1;    // K half of the chunk
    const int rg   = w >> 2;          // row half
    const int rb   = blockIdx.x * MROWS;
    const int fr32 = lane & 31;
    const int fo   = lane >> 5;

    __shared__ char LDSRAW[34816];    // X tiles (32 KB) then scoreboard (34 KB)
    char* XH = LDSRAW;                // 16 KB [64][256B swizzled] bf16-hi
    char* XL = LDSRAW + 16384;        // 16 KB bf16-lo

    // staging coords: X 16 f32/thread (64 rows x 128 k f32 = 32 KB)
    const int srow = tid >> 3;               // 0..63
    const int sc16 = (tid & 7) * 16;         // f32 col base
    const float* xg = X + (size_t)(rb + srow) * H_DIM + sc16;
    const int xsw   = (srow & 15) << 4;
    const int xb0   = srow * 256 + ((sc16 * 2) ^ xsw);
    const int xb1   = srow * 256 + ((sc16 * 2 + 16) ^ xsw);

    // W frag pointer: per wave-quarter, per chunk: 8 x 1KB coalesced slots
    const char* wfg = (const char*)WS + (size_t)(w & 3) * 8192 + (size_t)lane * 16;

    const int arow = rg * 32 + fr32;
    const int asw  = (arow & 15) << 4;

    f32x16 acc;
#pragma unroll
    for (int r = 0; r < 16; ++r) acc[r] = 0.f;

    // ---- prologue: chunk-0 registers ----
    float4 px0 = *(const float4*)(xg);
    float4 px1 = *(const float4*)(xg + 4);
    float4 px2 = *(const float4*)(xg + 8);
    float4 px3 = *(const float4*)(xg + 12);
    short8v cA0, cA1, cA2, cA3, cA4, cA5, cA6, cA7;
    short8v cB0, cB1, cB2, cB3, cB4, cB5, cB6, cB7;
    cA0 = *(const short8v*)(wfg);
    cA1 = *(const short8v*)(wfg + 1024);
    cA2 = *(const short8v*)(wfg + 2048);
    cA3 = *(const short8v*)(wfg + 3072);
    cA4 = *(const short8v*)(wfg + 4096);
    cA5 = *(const short8v*)(wfg + 5120);
    cA6 = *(const short8v*)(wfg + 6144);
    cA7 = *(const short8v*)(wfg + 7168);

#define SPLIT8(PA, PB, DST) do {                                             \
        float v[8] = {PA.x, PA.y, PA.z, PA.w, PB.x, PB.y, PB.z, PB.w};       \
        ushort8v hv, lv;                                                     \
        _Pragma("unroll")                                                    \
        for (int t = 0; t < 8; ++t) {                                        \
            const unsigned short hb = f2bf(v[t]);                            \
            hv[t] = hb;                                                      \
            lv[t] = f2bf(v[t] - bf2f(hb));                                   \
        }                                                                    \
        *(ushort8v*)(XH + (DST)) = hv;                                       \
        *(ushort8v*)(XL + (DST)) = lv;                                       \
    } while (0)

#define KSTEP(KS, BH, BL) do {                                               \
        const int kb = kh * 128 + (KS) * 32 + fo * 16;                       \
        short8v ah = *(const short8v*)(XH + arow * 256 + (kb ^ asw));        \
        short8v al = *(const short8v*)(XL + arow * 256 + (kb ^ asw));        \
        acc = __builtin_amdgcn_mfma_f32_32x32x16_bf16(ah, BH, acc, 0, 0, 0); \
        acc = __builtin_amdgcn_mfma_f32_32x32x16_bf16(ah, BL, acc, 0, 0, 0); \
        acc = __builtin_amdgcn_mfma_f32_32x32x16_bf16(al, BH, acc, 0, 0, 0); \
    } while (0)

#define STEP(CH, C0, C1, C2, C3, C4, C5, C6, C7,                             \
                  N0, N1, N2, N3, N4, N5, N6, N7) do {                       \
        __syncthreads();   /* [A] prev compute done reading LDS */           \
        SPLIT8(px0, px1, xb0);                                               \
        SPLIT8(px2, px3, xb1);                                               \
        __syncthreads();   /* [B] X tile ready */                            \
        if ((CH) + 1 < NCH) {                                                \
            const float* xn = xg + ((CH) + 1) * KC;                          \
            px0 = *(const float4*)(xn);                                      \
            px1 = *(const float4*)(xn + 4);                                  \
            px2 = *(const float4*)(xn + 8);                                  \
            px3 = *(const float4*)(xn + 12);                                 \
            const char* wi = wfg + (size_t)((CH) + 1) * WIMG;                \
            N0 = *(const short8v*)(wi);                                      \
            N1 = *(const short8v*)(wi + 1024);                               \
            N2 = *(const short8v*)(wi + 2048);                               \
            N3 = *(const short8v*)(wi + 3072);                               \
            N4 = *(const short8v*)(wi + 4096);                               \
            N5 = *(const short8v*)(wi + 5120);                               \
            N6 = *(const short8v*)(wi + 6144);                               \
            N7 = *(const short8v*)(wi + 7168);                               \
        }                                                                    \
        KSTEP(0, C0, C1);                                                    \
        KSTEP(1, C2, C3);                                                    \
        KSTEP(2, C4, C5);                                                    \
        KSTEP(3, C6, C7);                                                    \
    } while (0)

    for (int ch = 0; ch < NCH; ch += 2) {
        STEP(ch,     cA0, cA1, cA2, cA3, cA4, cA5, cA6, cA7,
                     cB0, cB1, cB2, cB3, cB4, cB5, cB6, cB7);
        STEP(ch + 1, cB0, cB1, cB2, cB3, cB4, cB5, cB6, cB7,
                     cA0, cA1, cA2, cA3, cA4, cA5, cA6, cA7);
    }
#undef STEP
#undef KSTEP
#undef SPLIT8

    // ---- scoreboard: 2 kh-planes [2][64][68] f32, deterministic reduce ----
    __syncthreads();                       // all compute done
    float* sm = (float*)LDSRAW;            // 34816 B exactly
    // C/D layout (m74/m101): col = lane&31, row = (r&3)+8*(r>>2)+4*(lane>>5)
#pragma unroll
    for (int r = 0; r < 16; ++r) {
        const int row = (r & 3) + 8 * (r >> 2) + 4 * fo;
        sm[(kh * 64 + rg * 32 + row) * 68 + cg * 32 + fr32] = acc[r];
    }
    __syncthreads();
    if (w >= 4) return;                    // no barriers after this point

    const unsigned long long mbits =
        *(const unsigned long long*)((const char*)WS + MASK_OFF);

    const int fr = lane & 15;
    const int fq = lane >> 4;
    float* o_log = out;
    float* o_rw  = out + (size_t)T_ROWS * E_NUM;
    float* o_se  = o_rw + (size_t)T_ROWS * TOPK;

    // wave w handles rows w*16 .. w*16+15 with the value-verified epilogue
#pragma unroll
    for (int j = 0; j < 4; ++j) {
        const int row_l = w * 16 + fq * 4 + j;
        const int grow  = rb + row_l;
        float a0 = 0.f, a1 = 0.f, a2 = 0.f, a3 = 0.f;
#pragma unroll
        for (int p = 0; p < 2; ++p) {      // fixed-order kh reduction
            a0 += sm[(p * 64 + row_l) * 68 +  0 + fr];
            a1 += sm[(p * 64 + row_l) * 68 + 16 + fr];
            a2 += sm[(p * 64 + row_l) * 68 + 32 + fr];
            a3 += sm[(p * 64 + row_l) * 68 + 48 + fr];
        }
        float mv0 = ((mbits >> ( 0 + fr)) & 1) ? a0 : -10000.0f;
        float mv1 = ((mbits >> (16 + fr)) & 1) ? a1 : -10000.0f;
        float mv2 = ((mbits >> (32 + fr)) & 1) ? a2 : -10000.0f;
        float mv3 = ((mbits >> (48 + fr)) & 1) ? a3 : -10000.0f;
        o_log[(size_t)grow * 64 +  0 + fr] = mv0;
        o_log[(size_t)grow * 64 + 16 + fr] = mv1;
        o_log[(size_t)grow * 64 + 32 + fr] = mv2;
        o_log[(size_t)grow * 64 + 48 + fr] = mv3;

        float m = fmaxf(fmaxf(mv0, mv1), fmaxf(mv2, mv3));
#pragma unroll
        for (int off = 1; off < 16; off <<= 1) m = fmaxf(m, __shfl_xor(m, off));

        float tsum = 0.f, myv = 0.f;
        int   mye  = 0;
#pragma unroll
        for (int t = 0; t < TOPK; ++t) {
            float bv = mv0; int be = fr;
            if (mv1 > bv) { bv = mv1; be = 16 + fr; }
            if (mv2 > bv) { bv = mv2; be = 32 + fr; }
            if (mv3 > bv) { bv = mv3; be = 48 + fr; }
#pragma unroll
            for (int off = 1; off < 16; off <<= 1) {
                float ov = __shfl_xor(bv, off);
                int   oe = __shfl_xor(be, off);
                if (ov > bv || (ov == bv && oe < be)) { bv = ov; be = oe; }
            }
            const float pv = expf(bv - m);
            tsum += pv;
            if (fr == t) { myv = pv; mye = be; }
            if ((be & 15) == fr) {       // owner lane excludes winner
                const int bn = be >> 4;
                if      (bn == 0) mv0 = -3.4e38f;
                else if (bn == 1) mv1 = -3.4e38f;
                else if (bn == 2) mv2 = -3.4e38f;
                else              mv3 = -3.4e38f;
            }
        }
        if (fr < TOPK) {
            o_rw[(size_t)grow * TOPK + fr] = myv / tsum;
            o_se[(size_t)grow * TOPK + fr] = (float)mye;
        }
    }
}

extern "C" void kernel_launch(void* const* d_in, const int* in_sizes, int n_in,
                              void* d_out, int out_size, void* d_ws, size_t ws_size,
                              hipStream_t stream) {
    const float* X   = (const float*)d_in[0];
    const float* W   = (const float*)d_in[1];
    const int*   ids = (const int*)d_in[2];
    const int    nids = in_sizes[2];
    float* out = (float*)d_out;

    unsigned short* WS = (unsigned short*)d_ws;   // 1 MB W image + 8 B mask

    hipLaunchKernelGGL(prep_w, dim3(256), dim3(256), 0, stream, W, WS, ids, nids);
    hipLaunchKernelGGL(router_main, dim3(T_ROWS / MROWS), dim3(512), 0, stream,
                       X, WS, out);
}

// Round 16
// 84.263 us; speedup vs baseline: 1.1436x; 1.1180x over previous
//
#include <hip/hip_runtime.h>
#include <hip/hip_bf16.h>

typedef __attribute__((ext_vector_type(16))) float f32x16;
typedef __attribute__((ext_vector_type(8))) short short8v;
typedef __attribute__((ext_vector_type(8))) unsigned short ushort8v;

#define T_ROWS 16384
#define H_DIM  4096
#define E_NUM  64
#define TOPK   8
#define MROWS  32               // rows per block
#define KC     128              // k-chunk
#define NCH    (H_DIM / KC)     // 32 chunks
#define WIMG   16384            // bytes per W chunk image (hi plane only)
#define MASK_OFF ((size_t)NCH * WIMG)

__device__ __forceinline__ unsigned short f2bf(float f) {
    unsigned int u = __float_as_uint(f);
    unsigned int r = (u + 0x7fffu + ((u >> 16) & 1u)) >> 16;  // RNE
    return (unsigned short)r;
}
__device__ __forceinline__ float bf2f(unsigned short h) {
    return __uint_as_float(((unsigned int)h) << 16);
}

// ---- prep: frag-slot-ordered W image (bf16 HI ONLY) + allowed-mask ----
// image[ch 0..31][w 0..7][j 0..1][lane 0..63]*16B ; role w: cg=w&1, kh=w>>1 ;
// slot j = ks (0..1). Value: 8 bf16-hi of
// W[cg*32+(lane&31)][ch*128 + kh*32 + ks*16 + (lane>>5)*8 ...]
__global__ __launch_bounds__(256) void prep_w(
    const float* __restrict__ W, unsigned short* __restrict__ WS,
    const int* __restrict__ ids, int nids)
{
    const int g    = blockIdx.x * 256 + threadIdx.x;   // 32768 16B-groups
    const int lane = g & 63;
    const int j    = (g >> 6) & 1;
    const int w    = (g >> 7) & 7;
    const int ch   = g >> 10;
    const int row  = (w & 1) * 32 + (lane & 31);
    const int kk   = ch * KC + (w >> 1) * 32 + j * 16 + (lane >> 5) * 8;
    const float* src = W + (size_t)row * H_DIM + kk;
    ushort8v o;
#pragma unroll
    for (int t = 0; t < 8; ++t) o[t] = f2bf(src[t]);
    *(ushort8v*)((char*)WS + (size_t)g * 16) = o;

    if (blockIdx.x == 0 && threadIdx.x == 0) {
        unsigned long long mb = 0;
        for (int t = 0; t < nids; ++t) {
            const int e = ids[t];
            if (e >= 0 && e < E_NUM) mb |= (1ull << e);
        }
        *(unsigned long long*)((char*)WS + MASK_OFF) = mb;
    }
}

// ---- main: 512 thr = 8 waves; wave (cg=w&1, kh=w>>1) computes a 32x32
// partial over K-quarter kh with mfma_32x32x16; W-hi frags global->regs;
// X split hi/lo (exact) staged via LDS. ----
__global__ __launch_bounds__(512, 4) void router_main(
    const float* __restrict__ X, const unsigned short* __restrict__ WS,
    float* __restrict__ out)
{
    const int tid  = threadIdx.x;
    const int lane = tid & 63;
    const int w    = tid >> 6;        // 0..7
    const int cg   = w & 1;           // experts half
    const int kh   = w >> 1;          // K quarter of the chunk
    const int rb   = blockIdx.x * MROWS;
    const int fr32 = lane & 31;
    const int fo   = lane >> 5;

    __shared__ char LDSRAW[34816];    // X tiles (16 KB) then scoreboard (34 KB)
    char* XH = LDSRAW;                // 8 KB [32][256B swizzled] bf16-hi
    char* XL = LDSRAW + 8192;         // 8 KB bf16-lo

    // staging coords: X 8 f32/thread
    const int srow = tid >> 4;               // 0..31
    const int sc8  = (tid & 15) * 8;         // f32 col base
    const float* xg = X + (size_t)(rb + srow) * H_DIM + sc8;
    const int xbyte = srow * 256 + ((sc8 * 2) ^ ((srow & 15) << 4));

    // W frag pointer: per wave, per chunk: 2 x 1KB coalesced slots
    const char* wfg = (const char*)WS + (size_t)w * 2048 + (size_t)lane * 16;

    const int arow = fr32;
    const int asw  = (arow & 15) << 4;

    f32x16 acc;
#pragma unroll
    for (int r = 0; r < 16; ++r) acc[r] = 0.f;

    // ---- prologue: chunk-0 registers ----
    float4 px0 = *(const float4*)(xg);
    float4 px1 = *(const float4*)(xg + 4);
    short8v cA0, cA1, cB0, cB1;
    cA0 = *(const short8v*)(wfg);
    cA1 = *(const short8v*)(wfg + 1024);

#define STEP(CH, C0, C1, N0, N1) do {                                        \
        __syncthreads();   /* [A] prev compute done reading LDS */           \
        {                                                                    \
            float v[8] = {px0.x, px0.y, px0.z, px0.w,                        \
                          px1.x, px1.y, px1.z, px1.w};                       \
            ushort8v hv, lv;                                                 \
            _Pragma("unroll")                                                \
            for (int t = 0; t < 8; ++t) {                                    \
                const unsigned short hb = f2bf(v[t]);                        \
                hv[t] = hb;                                                  \
                lv[t] = f2bf(v[t] - bf2f(hb));                               \
            }                                                                \
            *(ushort8v*)(XH + xbyte) = hv;                                   \
            *(ushort8v*)(XL + xbyte) = lv;                                   \
        }                                                                    \
        __syncthreads();   /* [B] X tile ready */                            \
        if ((CH) + 1 < NCH) {                                                \
            const float* xn = xg + ((CH) + 1) * KC;                          \
            px0 = *(const float4*)(xn);                                      \
            px1 = *(const float4*)(xn + 4);                                  \
            const char* wi = wfg + (size_t)((CH) + 1) * WIMG;                \
            N0 = *(const short8v*)(wi);                                      \
            N1 = *(const short8v*)(wi + 1024);                               \
        }                                                                    \
        {                                                                    \
            const int kb0 = kh * 64 + fo * 16;                               \
            short8v ah = *(const short8v*)(XH + arow * 256 + (kb0 ^ asw));   \
            short8v al = *(const short8v*)(XL + arow * 256 + (kb0 ^ asw));   \
            acc = __builtin_amdgcn_mfma_f32_32x32x16_bf16(ah, C0, acc, 0, 0, 0); \
            acc = __builtin_amdgcn_mfma_f32_32x32x16_bf16(al, C0, acc, 0, 0, 0); \
            const int kb1 = kb0 + 32;                                        \
            short8v ah1 = *(const short8v*)(XH + arow * 256 + (kb1 ^ asw));  \
            short8v al1 = *(const short8v*)(XL + arow * 256 + (kb1 ^ asw));  \
            acc = __builtin_amdgcn_mfma_f32_32x32x16_bf16(ah1, C1, acc, 0, 0, 0); \
            acc = __builtin_amdgcn_mfma_f32_32x32x16_bf16(al1, C1, acc, 0, 0, 0); \
        }                                                                    \
    } while (0)

    for (int ch = 0; ch < NCH; ch += 2) {
        STEP(ch,     cA0, cA1, cB0, cB1);
        STEP(ch + 1, cB0, cB1, cA0, cA1);
    }
#undef STEP

    // ---- scoreboard: 4 kh-planes [4][32][68] f32, deterministic reduce ----
    __syncthreads();                       // all compute done
    float* sm = (float*)LDSRAW;            // 34816 B exactly
    // C/D layout (m74/m101): col = lane&31, row = (r&3)+8*(r>>2)+4*(lane>>5)
#pragma unroll
    for (int r = 0; r < 16; ++r) {
        const int row = (r & 3) + 8 * (r >> 2) + 4 * fo;
        sm[(kh * 32 + row) * 68 + cg * 32 + fr32] = acc[r];
    }
    __syncthreads();
    if (w >= 2) return;                    // no barriers after this point

    const unsigned long long mbits =
        *(const unsigned long long*)((const char*)WS + MASK_OFF);

    const int fr = lane & 15;
    const int fq = lane >> 4;
    float* o_log = out;
    float* o_rw  = out + (size_t)T_ROWS * E_NUM;
    float* o_se  = o_rw + (size_t)T_ROWS * TOPK;

    // wave w handles rows w*16 .. w*16+15 with the value-verified epilogue
#pragma unroll
    for (int j = 0; j < 4; ++j) {
        const int row_l = w * 16 + fq * 4 + j;
        const int grow  = rb + row_l;
        float a0 = 0.f, a1 = 0.f, a2 = 0.f, a3 = 0.f;
#pragma unroll
        for (int p = 0; p < 4; ++p) {      // fixed-order kh reduction
            a0 += sm[(p * 32 + row_l) * 68 +  0 + fr];
            a1 += sm[(p * 32 + row_l) * 68 + 16 + fr];
            a2 += sm[(p * 32 + row_l) * 68 + 32 + fr];
            a3 += sm[(p * 32 + row_l) * 68 + 48 + fr];
        }
        float mv0 = ((mbits >> ( 0 + fr)) & 1) ? a0 : -10000.0f;
        float mv1 = ((mbits >> (16 + fr)) & 1) ? a1 : -10000.0f;
        float mv2 = ((mbits >> (32 + fr)) & 1) ? a2 : -10000.0f;
        float mv3 = ((mbits >> (48 + fr)) & 1) ? a3 : -10000.0f;
        o_log[(size_t)grow * 64 +  0 + fr] = mv0;
        o_log[(size_t)grow * 64 + 16 + fr] = mv1;
        o_log[(size_t)grow * 64 + 32 + fr] = mv2;
        o_log[(size_t)grow * 64 + 48 + fr] = mv3;

        float m = fmaxf(fmaxf(mv0, mv1), fmaxf(mv2, mv3));
#pragma unroll
        for (int off = 1; off < 16; off <<= 1) m = fmaxf(m, __shfl_xor(m, off));

        float tsum = 0.f, myv = 0.f;
        int   mye  = 0;
#pragma unroll
        for (int t = 0; t < TOPK; ++t) {
            float bv = mv0; int be = fr;
            if (mv1 > bv) { bv = mv1; be = 16 + fr; }
            if (mv2 > bv) { bv = mv2; be = 32 + fr; }
            if (mv3 > bv) { bv = mv3; be = 48 + fr; }
#pragma unroll
            for (int off = 1; off < 16; off <<= 1) {
                float ov = __shfl_xor(bv, off);
                int   oe = __shfl_xor(be, off);
                if (ov > bv || (ov == bv && oe < be)) { bv = ov; be = oe; }
            }
            const float pv = expf(bv - m);
            tsum += pv;
            if (fr == t) { myv = pv; mye = be; }
            if ((be & 15) == fr) {       // owner lane excludes winner
                const int bn = be >> 4;
                if      (bn == 0) mv0 = -3.4e38f;
                else if (bn == 1) mv1 = -3.4e38f;
                else if (bn == 2) mv2 = -3.4e38f;
                else              mv3 = -3.4e38f;
            }
        }
        if (fr < TOPK) {
            o_rw[(size_t)grow * TOPK + fr] = myv / tsum;
            o_se[(size_t)grow * TOPK + fr] = (float)mye;
        }
    }
}

extern "C" void kernel_launch(void* const* d_in, const int* in_sizes, int n_in,
                              void* d_out, int out_size, void* d_ws, size_t ws_size,
                              hipStream_t stream) {
    const float* X   = (const float*)d_in[0];
    const float* W   = (const float*)d_in[1];
    const int*   ids = (const int*)d_in[2];
    const int    nids = in_sizes[2];
    float* out = (float*)d_out;

    unsigned short* WS = (unsigned short*)d_ws;   // 0.5 MB W image + 8 B mask

    hipLaunchKernelGGL(prep_w, dim3(128), dim3(256), 0, stream, W, WS, ids, nids);
    hipLaunchKernelGGL(router_main, dim3(T_ROWS / MROWS), dim3(512), 0, stream,
                       X, WS, out);
}